// Round 3
// baseline (60.035 us; speedup 1.0000x reference)
//
#include <hip/hip_runtime.h>

// OrNet resonate-and-fire, B=32768, T=1000.
//
// Structure (derived from the reference recurrence, verified bit-exact in R1, absmax=0.0):
//  * Each neuron depends on inputs only via n_on = (x1>0)+(x2>0) in {0,1,2}.
//  * Pulse schedule: z=0 except t=32 (z = 20*(2-n_on)) and t=64 (z = z_on+z_off = 40,
//    the SAME for every case since both trains fire).
//  * After the first pulse, mi goes positive one step later; the spike reset then pins
//    mr to 0 forever and mi decays geometrically by a = 1+DT*beta per step.
//    Latest event: t=66. So: exact fp32 sim of t=0..66 (same op order as reference),
//    then closed-form decay out = mi_66 * a^933 computed in fp64 (rounds to the exact
//    same float as 933 iterated fp32 multiplies -- verified absmax == 0.0 in R1).
//  * Only 3 distinct trajectories exist -> simulate all 3 cases once per thread with
//    3-way ILP (chain latency unchanged), select per element. float4 I/O, 4 elem/thread.

#define T_TOTAL   1000
#define SIM_STEPS 67
#define REMAIN    (T_TOTAL - SIM_STEPS)   // 933 pure-decay steps

__global__ __launch_bounds__(256)
void ornet_kernel(const float4* __restrict__ x1,
                  const float4* __restrict__ x2,
                  const float* __restrict__ params,
                  float4* __restrict__ out,
                  int B4)
{
    int i = blockIdx.x * blockDim.x + threadIdx.x;
    if (i >= B4) return;

    const float DT = 0.01f;

    float beta = params[0];
    float freq = params[1];

    // --- simulate the 3 cases (n_on = 0,1,2) with ILP; z32 = 20*(2-n_on), z64 = 40 ---
    float mr0 = 0.f, mi0 = 0.f;
    float mr1 = 0.f, mi1 = 0.f;
    float mr2 = 0.f, mi2 = 0.f;
#pragma unroll
    for (int t = 0; t < SIM_STEPS; ++t) {
        float z64 = (t == 64) ? 40.0f : 0.0f;
        float z0 = (t == 32) ? 40.0f : z64;   // n_on=0: z_off=40 at t=32
        float z1 = (t == 32) ? 20.0f : z64;   // n_on=1: z_off=20 at t=32
        float z2 = z64;                        // n_on=2: nothing at t=32
        // exact reference op order:
        float mr0n = mr0 + DT * (beta * mr0 - freq * mi0 + z0);
        float mi0n = mi0 + DT * (freq * mr0 + beta * mi0);
        float mr1n = mr1 + DT * (beta * mr1 - freq * mi1 + z1);
        float mi1n = mi1 + DT * (freq * mr1 + beta * mi1);
        float mr2n = mr2 + DT * (beta * mr2 - freq * mi2 + z2);
        float mi2n = mi2 + DT * (freq * mr2 + beta * mi2);
        mr0 = (mi0n > 0.f) ? 0.f : mr0n;  mi0 = mi0n;
        mr1 = (mi1n > 0.f) ? 0.f : mr1n;  mi1 = mi1n;
        mr2 = (mi2n > 0.f) ? 0.f : mr2n;  mi2 = mi2n;
    }

    // --- closed-form decay: a^REMAIN in fp64 by repeated squaring ---
    double a = 1.0 + (double)DT * (double)beta;
    double p = 1.0, base_ = a;
    int e = REMAIN;
    while (e) {
        if (e & 1) p *= base_;
        base_ *= base_;
        e >>= 1;
    }

    float r0 = (float)((double)mi0 * p);
    float r1 = (float)((double)mi1 * p);
    float r2 = (float)((double)mi2 * p);

    // --- per-element select ---
    float4 a1 = x1[i];
    float4 a2 = x2[i];
    float4 o;
    {
        int n;
        n = (a1.x > 0.f) + (a2.x > 0.f);  o.x = (n == 0) ? r0 : ((n == 1) ? r1 : r2);
        n = (a1.y > 0.f) + (a2.y > 0.f);  o.y = (n == 0) ? r0 : ((n == 1) ? r1 : r2);
        n = (a1.z > 0.f) + (a2.z > 0.f);  o.z = (n == 0) ? r0 : ((n == 1) ? r1 : r2);
        n = (a1.w > 0.f) + (a2.w > 0.f);  o.w = (n == 0) ? r0 : ((n == 1) ? r1 : r2);
    }
    out[i] = o;
}

extern "C" void kernel_launch(void* const* d_in, const int* in_sizes, int n_in,
                              void* d_out, int out_size, void* d_ws, size_t ws_size,
                              hipStream_t stream) {
    const float4* x1     = (const float4*)d_in[0];
    const float4* x2     = (const float4*)d_in[1];
    const float*  params = (const float*)d_in[2];
    float4* out = (float4*)d_out;

    int B  = in_sizes[0];
    int B4 = B / 4;                 // B = 32768, divisible by 4
    int threads = 256;
    int blocks = (B4 + threads - 1) / threads;

    hipLaunchKernelGGL(ornet_kernel, dim3(blocks), dim3(threads), 0, stream,
                       x1, x2, params, out, B4);
}